// Round 1
// baseline (302.620 us; speedup 1.0000x reference)
//
#include <hip/hip_runtime.h>

// Problem shape (fixed by setup_inputs):
//   tens:    (B=8, C=32, H=128, W=128) f32
//   filters: (S=16, 1, 7, 7)           f32
//   shifts:  (16, 2) int32 in [0,8)
//   out:     (B, C*S, H, W) = (8, 512, 128, 128) f32 -> 67,108,864 floats (268 MB)
//
// Verified analysis (R1 of prior session, absmax=0): the non-cyclic roll-mask
// keeps only wrapped rows sourced from the zero-padded region, so the shifted
// plane has at most ONE nonzero element, and the VALID 7x7 correlation leaves
// exactly one possibly-nonzero output per (n,s) plane:
//   out[b, c*16+s, 0, 0] = tens[b,c,127,127] * filters[s,0,0,0]  iff shifts[s]==(7,7)
// All other outputs are exactly zero.
//
// R3 (this round): the previous memset used out_size*sizeof(float), but
// rocprof WRITE_SIZE showed 1.074 GB per fill = 4x the 268 MB output ->
// out_size is already BYTES. Instead of relying on the unit convention,
// hard-code the known output size and fuse zero-fill + corner-patch into a
// single grid-stride float4 store kernel:
//   - 16,777,216 float4 stores (268 MB), pure streaming writes (fill path
//     showed ~14 KB FETCH for 1 GB written => no read-for-ownership cost).
//   - corner elements sit at float4 index f with (f & 4095)==0; the thread
//     that zeroes that float4 writes the patched .x -> no race, no 2nd kernel.

#define HW       16384u     // 128*128 plane elements
#define CS       512u       // C*S output channels
#define C_       32u
#define S_       16u
#define TOTAL_F4 16777216u  // 67,108,864 floats / 4

__global__ __launch_bounds__(256) void zero_and_patch(
    const float* __restrict__ tens,
    const float* __restrict__ filters,
    const int*   __restrict__ shifts,
    float4*      __restrict__ out)
{
    unsigned t = blockIdx.x * blockDim.x + threadIdx.x;
    unsigned stride = gridDim.x * blockDim.x;   // 524,288 threads -> 32 f4/thread

    for (unsigned f = t; f < TOTAL_F4; f += stride) {
        float4 v = make_float4(0.f, 0.f, 0.f, 0.f);
        if ((f & 4095u) == 0u) {               // first float4 of a 16384-elem plane
            unsigned plane = f >> 12;          // 0 .. 4095  (b*512 + c*16 + s)
            unsigned ch = plane & (CS - 1u);
            unsigned b  = plane >> 9;
            unsigned c  = ch >> 4;
            unsigned s  = ch & (S_ - 1u);
            int sy = shifts[2u * s];
            int sx = shifts[2u * s + 1u];
            if (sy == 7 && sx == 7) {
                unsigned n = b * C_ + c;
                v.x = tens[(size_t)n * HW + (HW - 1u)] * filters[s * 49u];
            }
        }
        out[f] = v;
    }
}

extern "C" void kernel_launch(void* const* d_in, const int* in_sizes, int n_in,
                              void* d_out, int out_size, void* d_ws, size_t ws_size,
                              hipStream_t stream) {
    const float* tens    = (const float*)d_in[0];
    const float* filters = (const float*)d_in[1];
    const int*   shifts  = (const int*)d_in[2];
    float4*      out     = (float4*)d_out;

    // Memory-bound: cap grid at 2048 blocks (8 blocks/CU across 256 CUs),
    // grid-stride the 16.7M float4 stores.
    zero_and_patch<<<dim3(2048), dim3(256), 0, stream>>>(tens, filters, shifts, out);
}

// Round 2
// 264.719 us; speedup vs baseline: 1.1432x; 1.1432x over previous
//
#include <hip/hip_runtime.h>

// Problem shape (fixed by setup_inputs):
//   tens:    (B=8, C=32, H=128, W=128) f32
//   filters: (S=16, 1, 7, 7)           f32
//   shifts:  (16, 2) int32 in [0,8)
//   out:     (B, C*S, H, W) = (8, 512, 128, 128) f32
//          = 67,108,864 floats = 268,435,456 bytes (exact, hard-coded below)
//
// Verified analysis (absmax=0 across all rounds): the non-cyclic roll-mask
// keeps only wrapped rows sourced from the zero-padded region, so the shifted
// plane has at most ONE nonzero element, and the VALID 7x7 correlation leaves
// exactly one possibly-nonzero output per (n,s) plane:
//   out[b, c*16+s, 0, 0] = tens[b,c,127,127] * filters[s,0,0,0]  iff shifts[s]==(7,7)
// All other outputs are exactly zero.
//
// R4 (this round): R1's fused grid-stride store kernel ran at ~3.7 TB/s vs
// the rocclr fillBuffer path's 6.4 TB/s -> revert to memset + tiny patch.
// The persistent 1.074 GB fillBuffer dispatches are the HARNESS's re-poison
// (present even with no memset in our code), so they are outside our control.
// Remaining ambiguity: out_size elements-vs-bytes. Hard-coding the known
// 268,435,456-byte output size is correct under both conventions, and saves
// ~125 us if R0's out_size*sizeof(float) was silently writing 1.074 GB.

#define OUT_BYTES 268435456ull   // 8*512*128*128 * 4
#define HW    16384      // 128*128 plane elements
#define CS    512        // C*S output channels
#define C_    32
#define S_    16

__global__ __launch_bounds__(256) void corner_patch(
    const float* __restrict__ tens,
    const float* __restrict__ filters,
    const int*   __restrict__ shifts,
    float*       __restrict__ out)
{
    int plane = blockIdx.x * blockDim.x + threadIdx.x;   // 0 .. 4095
    int ch = plane & (CS - 1);     // plane % 512
    int b  = plane >> 9;           // plane / 512
    int c  = ch >> 4;              // ch / 16
    int s  = ch & (S_ - 1);        // ch % 16
    int sy = shifts[2 * s];
    int sx = shifts[2 * s + 1];
    if (sy == 7 && sx == 7) {
        int n = b * C_ + c;
        out[(long long)plane * HW] =
            tens[(long long)n * HW + (HW - 1)] * filters[s * 49];
    }
}

extern "C" void kernel_launch(void* const* d_in, const int* in_sizes, int n_in,
                              void* d_out, int out_size, void* d_ws, size_t ws_size,
                              hipStream_t stream) {
    const float* tens    = (const float*)d_in[0];
    const float* filters = (const float*)d_in[1];
    const int*   shifts  = (const int*)d_in[2];
    float*       out     = (float*)d_out;

    // Zero the exact 268 MB output on the proven 6.4 TB/s fillBuffer path.
    // Hard-coded byte count: immune to the out_size elements-vs-bytes
    // convention (and saves ~125 us if out_size was already bytes).
    hipMemsetAsync(out, 0, OUT_BYTES, stream);

    // Patch the <=4096 possibly-nonzero corner elements (one thread/plane).
    corner_patch<<<dim3(16), dim3(256), 0, stream>>>(tens, filters, shifts, out);
}